// Round 2
// baseline (218.212 us; speedup 1.0000x reference)
//
#include <hip/hip_runtime.h>
#include <stdint.h>

// 3x3 conv s1 p1, NCHW fp32, 64->128 ch, 16x112x112.
// Implicit GEMM on bf16 MFMA with NHWC bf16 x-repack in d_ws:
//   prep:  x (NCHW fp32) -> x_t[(n*12544+p)*64+ic] bf16 ; w -> Wt[tap][oc][ic] bf16 ; 128B zero block
//   conv:  per block 128oc x 128px tile. Weights double-buffered in LDS (2x16KB, 1 barrier/tap).
//          X (B-fragments) read per-lane DIRECTLY from global (L2/L3-resident xt) - no X LDS,
//          so LDS=32.8KB + VGPR<=128 gives 4 blocks/CU (16 waves) for latency hiding.
//          Boundary pixels: per-lane source pointer cndmask'd to a 128B zero block.
//          vmcnt discipline: B loads issued BEFORE the W global_load_lds prefetch of the same
//          phase so waiting on B never drains W (in-order vmcnt retirement).

#define HW     112
#define PIX    12544
#define ICN    64
#define OCN    128
#define TILEP  128
#define PTILES 98
#define NBLK   1568
#define NIMG   16

#define XT_BYTES   (NIMG * PIX * ICN * 2)          // 25,690,112
#define WT_OFF     XT_BYTES
#define WT_BYTES   (9 * OCN * ICN * 2)             // 147,456
#define ZG_OFF     (WT_OFF + WT_BYTES)             // 128B zero block
#define XBLK       (NIMG * (PIX / 64))             // 3136 transpose blocks
#define WBLK       72                              // 72 * 1024 = 73728 weight elems

typedef __attribute__((ext_vector_type(8))) __bf16 bf16x8;
typedef __attribute__((ext_vector_type(4))) float  f32x4;

__device__ __forceinline__ uint32_t rne_lo(float f) {
    uint32_t u = __builtin_bit_cast(uint32_t, f);
    return (u + 0x7fffu + ((u >> 16) & 1u)) >> 16;
}
__device__ __forceinline__ uint32_t pk2(float a, float b) {
    uint32_t ub = __builtin_bit_cast(uint32_t, b);
    ub = (ub + 0x7fffu + ((ub >> 16) & 1u)) & 0xffff0000u;
    return rne_lo(a) | ub;
}

__device__ __forceinline__ void load_lds16(const void* g, void* l) {
    __builtin_amdgcn_global_load_lds(
        (const __attribute__((address_space(1))) uint32_t*)g,
        (__attribute__((address_space(3))) uint32_t*)l, 16, 0, 0);
}

// ---------------- prep: x transpose+cvt, weight transpose+cvt, zero block ----------------
__global__ void __launch_bounds__(256)
prep(const float* __restrict__ x, const float* __restrict__ w, uint8_t* __restrict__ ws) {
    const int b = blockIdx.x;
    const int t = threadIdx.x;
    uint16_t* xt = (uint16_t*)ws;
    uint16_t* wt = (uint16_t*)(ws + WT_OFF);

    if (b < XBLK) {
        // 64 pixels per block; thread: pixel = t>>2, ic chunk q = t&3 (16 ic each)
        const int n  = b / (PIX / 64);
        const int p0 = (b - n * (PIX / 64)) * 64;
        const int px = t >> 2;
        const int q  = t & 3;
        const float* src = x + ((size_t)n * ICN + q * 16) * PIX + p0 + px;
        float v[16];
#pragma unroll
        for (int i = 0; i < 16; ++i) v[i] = src[(size_t)i * PIX];
        uint4 u0 = make_uint4(pk2(v[0], v[1]),  pk2(v[2], v[3]),
                              pk2(v[4], v[5]),  pk2(v[6], v[7]));
        uint4 u1 = make_uint4(pk2(v[8], v[9]),  pk2(v[10], v[11]),
                              pk2(v[12], v[13]), pk2(v[14], v[15]));
        char* dst = (char*)xt + ((size_t)(n * PIX + p0 + px)) * 128 + q * 32;
        *(uint4*)dst        = u0;
        *(uint4*)(dst + 16) = u1;
    } else {
        const int wb = b - XBLK;
#pragma unroll
        for (int k = 0; k < 4; ++k) {
            int wi = wb * 1024 + k * 256 + t;          // [0, 73728)
            int r  = wi >> 13;
            int oc = (wi >> 6) & 127;
            int ic = wi & 63;
            wt[wi] = (uint16_t)rne_lo(w[oc * 576 + ic * 9 + r]);
        }
        if (wb == 0 && t < 8) ((uint4*)(ws + ZG_OFF))[t] = make_uint4(0, 0, 0, 0);
    }
}

// ---------------- main conv ----------------
__global__ void __launch_bounds__(256, 4)
conv_mfma(const uint8_t* __restrict__ ws, const float* __restrict__ bias,
          float* __restrict__ out) {
    __shared__ uint8_t Wb[2][16384];        // weights, double-buffered per tap

    const char* xt = (const char*)ws;
    const char* wt = (const char*)(ws + WT_OFF);
    const char* zg = (const char*)(ws + ZG_OFF);

    const int t = threadIdx.x;
    const int b = blockIdx.x;
    const int n_img = b / PTILES;
    const int p0 = (b - n_img * PTILES) * TILEP;

    const int lane = t & 63;
    const int wave = t >> 6;
    const int lr = lane & 15;
    const int lq = lane >> 4;
    const int oc_base = (wave & 1) * 64;
    const int px_base = (wave >> 1) * 64;

    // ---- weight staging geometry: row = (t>>3), chunk = t&7 (XOR-swizzled) ----
    const int rowB  = t >> 3;                        // 0..31
    const int cswz8 = ((t & 7) ^ (rowB & 7)) * 16;
    const char* wsrc = wt + rowB * 128 + cswz8;

    // ---- per-ni pixel geometry + per-lane global B base (lq chunk folded in) ----
    int hh[4], wwp[4];
    const char* xbase[4];
#pragma unroll
    for (int ni = 0; ni < 4; ++ni) {
        int p = p0 + px_base + ni * 16 + lr;
        int h = p / HW;
        hh[ni]  = h;
        wwp[ni] = p - h * HW;
        xbase[ni] = xt + ((ptrdiff_t)(n_img * PIX + p)) * 128 + lq * 16;
    }

    // ---- stage weights tap 0 -> Wb[0] ----
#pragma unroll
    for (int r2 = 0; r2 < 4; ++r2)
        load_lds16(wsrc + r2 * 4096, (char*)Wb + r2 * 4096 + wave * 1024);

    f32x4 acc[4][4];
    {
        f32x4 z = {0.f, 0.f, 0.f, 0.f};
#pragma unroll
        for (int i = 0; i < 4; ++i)
#pragma unroll
            for (int j = 0; j < 4; ++j) acc[i][j] = z;
    }

    __syncthreads();   // tap-0 weights staged (vmcnt(0)+barrier)

#pragma unroll
    for (int tap = 0; tap < 9; ++tap) {
        const int dy = tap / 3 - 1;
        const int dx = tap - (tap / 3) * 3 - 1;
        const int boff = (dy * HW + dx) * 128;

        // per-ni source pointer for this tap (boundary -> zero block)
        const char* bp[4];
#pragma unroll
        for (int ni = 0; ni < 4; ++ni) {
            bool ok = ((unsigned)(hh[ni] + dy) < HW) & ((unsigned)(wwp[ni] + dx) < HW);
            bp[ni] = ok ? (xbase[ni] + boff) : zg;
        }

        // kh=0 B-fragments from global FIRST (so their wait leaves W in flight)
        bf16x8 b0[4];
#pragma unroll
        for (int ni = 0; ni < 4; ++ni)
            b0[ni] = *(const bf16x8*)(bp[ni]);

        // prefetch next tap's weights into the other buffer
        if (tap < 8) {
#pragma unroll
            for (int r2 = 0; r2 < 4; ++r2)
                load_lds16(wsrc + (tap + 1) * 16384 + r2 * 4096,
                           (char*)Wb + ((tap + 1) & 1) * 16384 + r2 * 4096 + wave * 1024);
        }

        const char* wbase = (const char*)Wb + (tap & 1) * 16384;

        // ---- kh = 0 ----
        {
            const int cc = lq;                       // kh*4 + lq
            bf16x8 a_frag[4];
#pragma unroll
            for (int mi = 0; mi < 4; ++mi) {
                int R = oc_base + mi * 16 + lr;
                a_frag[mi] = *(const bf16x8*)(wbase + R * 128 + ((cc ^ (R & 7)) * 16));
            }
#pragma unroll
            for (int mi = 0; mi < 4; ++mi)
#pragma unroll
                for (int ni = 0; ni < 4; ++ni)
                    acc[mi][ni] = __builtin_amdgcn_mfma_f32_16x16x32_bf16(
                        a_frag[mi], b0[ni], acc[mi][ni], 0, 0, 0);
        }

        // ---- kh = 1 ----
        {
            bf16x8 b1[4];
#pragma unroll
            for (int ni = 0; ni < 4; ++ni)
                b1[ni] = *(const bf16x8*)(bp[ni] + 64);
            const int cc = 4 + lq;
            bf16x8 a_frag[4];
#pragma unroll
            for (int mi = 0; mi < 4; ++mi) {
                int R = oc_base + mi * 16 + lr;
                a_frag[mi] = *(const bf16x8*)(wbase + R * 128 + ((cc ^ (R & 7)) * 16));
            }
#pragma unroll
            for (int mi = 0; mi < 4; ++mi)
#pragma unroll
                for (int ni = 0; ni < 4; ++ni)
                    acc[mi][ni] = __builtin_amdgcn_mfma_f32_16x16x32_bf16(
                        a_frag[mi], b1[ni], acc[mi][ni], 0, 0, 0);
        }

        // one barrier per tap: drains W prefetch (covered by the 32 MFMAs above),
        // releases the buffer swap for tap+1.
        if (tap < 8) __syncthreads();
    }

    // ---- epilogue: D col = lane&15 -> pixel, row = lq*4+reg -> oc (validated R1)
#pragma unroll
    for (int mi = 0; mi < 4; ++mi) {
#pragma unroll
        for (int rg = 0; rg < 4; ++rg) {
            const int oc = oc_base + mi * 16 + lq * 4 + rg;
            const float bb = bias[oc];
            float* orow = out + ((size_t)n_img * OCN + oc) * PIX + p0 + px_base + lr;
#pragma unroll
            for (int ni = 0; ni < 4; ++ni)
                orow[ni * 16] = acc[mi][ni][rg] + bb;
        }
    }
}

extern "C" void kernel_launch(void* const* d_in, const int* in_sizes, int n_in,
                              void* d_out, int out_size, void* d_ws, size_t ws_size,
                              hipStream_t stream) {
    const float* x    = (const float*)d_in[0];
    const float* w    = (const float*)d_in[1];
    const float* bias = (const float*)d_in[2];
    float* out = (float*)d_out;
    uint8_t* ws = (uint8_t*)d_ws;   // needs ZG_OFF + 128 = 25,837,696 bytes

    prep<<<XBLK + WBLK, 256, 0, stream>>>(x, w, ws);
    conv_mfma<<<NBLK, 256, 0, stream>>>(ws, bias, out);
}